// Round 16
// baseline (222.339 us; speedup 1.0000x reference)
//
#include <hip/hip_runtime.h>
#include <hip/hip_bf16.h>
#include <stdint.h>

typedef _Float16 f16x8 __attribute__((ext_vector_type(8)));
typedef __fp16 fp16x2_t __attribute__((ext_vector_type(2)));
typedef float f32x4 __attribute__((ext_vector_type(4)));

#define MFMA_F16(A, B, C) __builtin_amdgcn_mfma_f32_16x16x32_f16(A, B, C, 0, 0, 0)
#define GLOAD_LDS16(g, l)                                                     \
    __builtin_amdgcn_global_load_lds(                                         \
        (const __attribute__((address_space(1))) void*)(g),                   \
        (__attribute__((address_space(3))) void*)(l), 16, 0, 0)

constexpr int Bb = 4, Nn = 4096, Cc = 256;
constexpr int BQ = 128;          // q rows per block (8 waves x 16)
constexpr int BK = 64;           // k/v rows per tile
constexpr int NT = Nn / BK;
constexpr int KPAD = 256;        // 512B row stride; swizzle via pre-swizzled source
constexpr int VPAD = 64;         // 128B row stride; swizzle via pre-swizzled source
// LDS: 2*sK 65536 + 3*sVt 98304 = 163840 B (== 160KiB cap).

constexpr size_t ASZ = (size_t)2 * Bb * Nn * Cc;     // elems per ws array
constexpr size_t WS_NEED = ASZ * 2 * 3;              // bytes: hi + lo + vt

__device__ __forceinline__ uint32_t pk16(float a, float b) {
    union { fp16x2_t h; uint32_t u; } cv;
    cv.h = __builtin_amdgcn_cvt_pkrtz(a, b);
    return cv.u;
}

// v_permlane32_swap_b32: ret[0] = {L<32: a[L],    L>=32: b[L-32]}
//                        ret[1] = {L<32: a[L+32], L>=32: b[L]}
// Pure VALU — replaces ds_bpermute-based __shfl_xor(,32) to relieve the LDS pipe.
struct pl32_t { int x, y; };
__device__ __forceinline__ pl32_t pl32(int a, int b) {
    auto v = __builtin_amdgcn_permlane32_swap(a, b, false, false);
    return {(int)v[0], (int)v[1]};
}

// ---------------- prep: fp32 -> fp16 hi/lo + transposed hi ----------------
__global__ __launch_bounds__(256)
void prep_kernel(const float* __restrict__ xa, const float* __restrict__ xb,
                 _Float16* __restrict__ hi, _Float16* __restrict__ lo,
                 _Float16* __restrict__ vt)
{
    const int n0 = blockIdx.x * 64, c0 = blockIdx.y * 64, ib = blockIdx.z;
    const float* x = ((ib >> 2) == 0 ? xa : xb) + (size_t)(ib & 3) * Nn * Cc;
    const size_t base = (size_t)ib * Nn * Cc;
    __shared__ ushort tile[64][68];
    const int t = threadIdx.x;
    const int r0 = t >> 4;            // 0..15
    const int c4 = (t & 15) * 4;      // 0,4,..,60
    #pragma unroll
    for (int ii = 0; ii < 4; ++ii) {
        const int r = r0 + ii * 16;
        float4 v = *(const float4*)&x[(size_t)(n0 + r) * Cc + c0 + c4];
        float vv[4] = {v.x, v.y, v.z, v.w};
        union { _Float16 h[4]; uint2 q; } H, L;
        #pragma unroll
        for (int e = 0; e < 4; ++e) {
            _Float16 h = (_Float16)vv[e];
            H.h[e] = h;
            L.h[e] = (_Float16)(vv[e] - (float)h);
        }
        *(uint2*)&hi[base + (size_t)(n0 + r) * Cc + c0 + c4] = H.q;
        *(uint2*)&lo[base + (size_t)(n0 + r) * Cc + c0 + c4] = L.q;
        *(uint2*)&tile[r][c4] = H.q;
    }
    __syncthreads();
    const int j4 = (t & 15) * 4;
    #pragma unroll
    for (int ii = 0; ii < 4; ++ii) {
        const int cr = r0 + ii * 16;
        ushort4 o;
        o.x = tile[j4 + 0][cr]; o.y = tile[j4 + 1][cr];
        o.z = tile[j4 + 2][cr]; o.w = tile[j4 + 3][cr];
        *(ushort4*)&vt[base + (size_t)(c0 + cr) * Nn + n0 + j4] = o;
    }
}

// ---------------- main attention ----------------
// grid = 256 1-D; bid&7 = (dir,b): round-robin block->XCD dispatch groups all 32
// q-tiles of one (dir,b) on ONE XCD (K 2MB + V^T 2MB fit its 4MB L2; FETCH 163->49MB).
template<bool PREP>
__global__ __launch_bounds__(512, 1)
void attn_kernel(const float* __restrict__ xa, const float* __restrict__ xb,
                 const float* __restrict__ gamma_p, float* __restrict__ out,
                 const _Float16* __restrict__ hi, const _Float16* __restrict__ lo,
                 const _Float16* __restrict__ vt)
{
    const int bid = blockIdx.x;
    const int qtile = bid >> 3, b = bid & 3, dir = (bid >> 2) & 1;
    const float* qsrc = (dir == 0 ? xa : xb) + (size_t)b * Nn * Cc;
    const float* ksrc = (dir == 0 ? xb : xa) + (size_t)b * Nn * Cc;
    float* outp = out + (size_t)dir * Bb * Nn * Cc + (size_t)b * Nn * Cc;
    const int qib = dir * Bb + b;
    const int kib = (dir ^ 1) * Bb + b;
    const _Float16* qhiB = hi + (size_t)qib * Nn * Cc;
    const _Float16* qloB = lo + (size_t)qib * Nn * Cc;
    const _Float16* kB   = hi + (size_t)kib * Nn * Cc;
    const _Float16* vtB  = vt + (size_t)qib * Nn * Cc;   // V^T of q-source

    __shared__ _Float16 sK[2][BK][KPAD];    // K (fp16 hi); swizzled via source
    __shared__ _Float16 sVt[3][Cc][VPAD];   // sVt[c][m] = V[m][c]; swizzled via source

    const int t = threadIdx.x, lane = t & 63, w = t >> 6;
    const int l15 = lane & 15, g = lane >> 4;
    const int khalf = g * 8;
    const int rsw = (l15 & 7) << 3;         // read swizzle (row = *16 + l15)

    // ---- Q fragments, negated (MFMA yields logits = -E), fp16 hi/lo ----
    f16x8 qhi[8], qlo[8];
    const int qrow = qtile * BQ + w * 16 + l15;
    if constexpr (PREP) {
        #pragma unroll
        for (int j = 0; j < 8; ++j) {
            union { uint4 u; f16x8 h; } A, C2;
            A.u  = *(const uint4*)(qhiB + (size_t)qrow * Cc + j * 32 + khalf);
            C2.u = *(const uint4*)(qloB + (size_t)qrow * Cc + j * 32 + khalf);
            A.u.x ^= 0x80008000u; A.u.y ^= 0x80008000u; A.u.z ^= 0x80008000u; A.u.w ^= 0x80008000u;
            C2.u.x ^= 0x80008000u; C2.u.y ^= 0x80008000u; C2.u.z ^= 0x80008000u; C2.u.w ^= 0x80008000u;
            qhi[j] = A.h; qlo[j] = C2.h;
        }
    } else {
        const float* qb = qsrc + (size_t)qrow * Cc;
        #pragma unroll
        for (int j = 0; j < 8; ++j) {
            float4 v0 = *(const float4*)(qb + j * 32 + khalf);
            float4 v1 = *(const float4*)(qb + j * 32 + khalf + 4);
            float xv[8] = {v0.x, v0.y, v0.z, v0.w, v1.x, v1.y, v1.z, v1.w};
            #pragma unroll
            for (int e = 0; e < 8; ++e) {
                float xn = -xv[e];
                _Float16 h = (_Float16)xn;
                qhi[j][e] = h;
                qlo[j][e] = (_Float16)(xn - (float)h);
            }
        }
    }

    f32x4 O[16];
    #pragma unroll
    for (int i = 0; i < 16; ++i) O[i] = (f32x4){0.f, 0.f, 0.f, 0.f};
    float mrow = -INFINITY;     // running max for q-row l15 (S^T domain, per-lane)
    float lsum = 0.f;           // partial sum for q-row l15 over this lane's k-slice

    f32x4 S[4];                 // current S^T tile (constant-indexed only)
    f16x8 pa0, pa1;             // loop-carried P fragments (computed one region early)

    // ---- global_load_lds staging maps: linear LDS dest, pre-swizzled source ----
    const int krow0 = w * 8;
    const int klsub = lane >> 5;            // row within inst (0..1)
    int offK[4];
    #pragma unroll
    for (int i = 0; i < 4; ++i) {
        const int rsub = i * 2 + klsub;                     // row mod 8 (krow0 % 8 == 0)
        const int sc = ((lane & 31) * 8) ^ ((rsub & 7) << 3);
        offK[i] = (krow0 + rsub) * Cc + sc;
    }
    const int vrow0 = w * 32;
    const int vlsub = lane >> 3;            // row within inst (0..7) == row mod 8
    const int vcol  = ((lane & 7) * 8) ^ ((vlsub & 7) << 3);
    int offV[4];
    #pragma unroll
    for (int i = 0; i < 4; ++i)
        offV[i] = (vrow0 + i * 8 + vlsub) * Nn + vcol;

    auto stageK = [&](int bufi, int m0) {
        #pragma unroll
        for (int i = 0; i < 4; ++i)
            GLOAD_LDS16(kB + (size_t)m0 * Cc + offK[i], &sK[bufi][krow0 + i * 2][0]);
    };
    auto stageV = [&](int vbi, int m0) {
        #pragma unroll
        for (int i = 0; i < 4; ++i)
            GLOAD_LDS16(vtB + (size_t)m0 + offV[i], &sVt[vbi][vrow0 + i * 8][0]);
    };

    auto qkt = [&](int kb) {
        // S^T = K (-Q)^T : swapped operands. Lane (l15,g): q-row=l15, k=16s+4g+r.
        #pragma unroll
        for (int s = 0; s < 4; ++s) S[s] = (f32x4){0.f, 0.f, 0.f, 0.f};
        __builtin_amdgcn_s_setprio(1);
        #pragma unroll
        for (int j = 0; j < 8; ++j) {
            const int ko = j * 32 + khalf;
            f16x8 k0 = *(const f16x8*)&sK[kb][l15][ko ^ rsw];
            f16x8 k1 = *(const f16x8*)&sK[kb][16 + l15][ko ^ rsw];
            f16x8 k2 = *(const f16x8*)&sK[kb][32 + l15][ko ^ rsw];
            f16x8 k3 = *(const f16x8*)&sK[kb][48 + l15][ko ^ rsw];
            S[0] = MFMA_F16(k0, qhi[j], S[0]);
            S[1] = MFMA_F16(k1, qhi[j], S[1]);
            S[2] = MFMA_F16(k2, qhi[j], S[2]);
            S[3] = MFMA_F16(k3, qhi[j], S[3]);
            S[0] = MFMA_F16(k0, qlo[j], S[0]);
            S[1] = MFMA_F16(k1, qlo[j], S[1]);
            S[2] = MFMA_F16(k2, qlo[j], S[2]);
            S[3] = MFMA_F16(k3, qlo[j], S[3]);
        }
        __builtin_amdgcn_s_setprio(0);
    };

    auto softmax = [&]() {
        // consumes S -> produces pa0/pa1; updates mrow/lsum; rescales O (rare)
        float tm = fmaxf(fmaxf(fmaxf(S[0][0], S[0][1]), fmaxf(S[0][2], S[0][3])),
                         fmaxf(fmaxf(S[1][0], S[1][1]), fmaxf(S[1][2], S[1][3])));
        tm = fmaxf(tm, fmaxf(fmaxf(fmaxf(S[2][0], S[2][1]), fmaxf(S[2][2], S[2][3])),
                             fmaxf(fmaxf(S[3][0], S[3][1]), fmaxf(S[3][2], S[3][3]))));
        tm = fmaxf(tm, __shfl_xor(tm, 16, 64));
        {   // xor-32 max via permlane32_swap (VALU): max(ret.x, ret.y) == full swap-max
            pl32_t sm = pl32(__float_as_int(tm), __float_as_int(tm));
            tm = fmaxf(__int_as_float(sm.x), __int_as_float(sm.y));
        }
        const bool need = tm > mrow + 8.f;
        if (__any(need)) {      // rescale path (rare: defer-max THR=8)
            float mn = fmaxf(mrow, tm);
            float a = __expf(mrow - mn);
            mrow = mn;
            lsum *= a;
            const int base = lane & 48;
            const int g4 = (g & 3) * 4;
            float a0 = __shfl(a, base | (g4 + 0), 64);
            float a1 = __shfl(a, base | (g4 + 1), 64);
            float a2 = __shfl(a, base | (g4 + 2), 64);
            float a3 = __shfl(a, base | (g4 + 3), 64);
            #pragma unroll
            for (int i = 0; i < 16; ++i) {
                O[i][0] *= a0; O[i][1] *= a1; O[i][2] *= a2; O[i][3] *= a3;
            }
        }
        uint32_t P2[4][2];
        float ps = 0.f;
        #pragma unroll
        for (int s = 0; s < 4; ++s) {
            float p0 = __expf(S[s][0] - mrow);
            float p1 = __expf(S[s][1] - mrow);
            float p2 = __expf(S[s][2] - mrow);
            float p3 = __expf(S[s][3] - mrow);
            ps += (p0 + p1) + (p2 + p3);
            P2[s][0] = pk16(p0, p1);
            P2[s][1] = pk16(p2, p3);
        }
        lsum += ps;
        // butterfly: redistribute P into PV A-fragments (no LDS round-trip)
        // round 1 (xor16): full package from partner g^1
        uint32_t q00 = __shfl_xor(P2[0][0], 16, 64);
        uint32_t q01 = __shfl_xor(P2[0][1], 16, 64);
        uint32_t q10 = __shfl_xor(P2[1][0], 16, 64);
        uint32_t q11 = __shfl_xor(P2[1][1], 16, 64);
        uint32_t q20 = __shfl_xor(P2[2][0], 16, 64);
        uint32_t q21 = __shfl_xor(P2[2][1], 16, 64);
        uint32_t q30 = __shfl_xor(P2[3][0], 16, 64);
        uint32_t q31 = __shfl_xor(P2[3][1], 16, 64);
        // round 2 (xor32) via permlane32_swap
        const bool low = (g < 2);
        const bool odd = (g & 1);
        uint32_t m0_ = low ? P2[1][0] : P2[0][0];
        uint32_t m1_ = low ? P2[1][1] : P2[0][1];
        uint32_t m2_ = low ? P2[3][0] : P2[2][0];
        uint32_t m3_ = low ? P2[3][1] : P2[2][1];
        uint32_t p0_ = low ? q10 : q00;
        uint32_t p1_ = low ? q11 : q01;
        uint32_t p2_ = low ? q30 : q20;
        uint32_t p3_ = low ? q31 : q21;
        uint32_t sl0 = odd ? p0_ : m0_, sh0 = odd ? m0_ : p0_;
        uint32_t sl1 = odd ? p1_ : m1_, sh1 = odd ? m1_ : p1_;
        uint32_t sl2 = odd ? p2_ : m2_, sh2 = odd ? m2_ : p2_;
        uint32_t sl3 = odd ? p3_ : m3_, sh3 = odd ? m3_ : p3_;
        pl32_t w0a = pl32((int)sl0, (int)sh0);
        pl32_t w0b = pl32((int)sh0, (int)sl0);
        pl32_t w1a = pl32((int)sl1, (int)sh1);
        pl32_t w1b = pl32((int)sh1, (int)sl1);
        pl32_t w2a = pl32((int)sl2, (int)sh2);
        pl32_t w2b = pl32((int)sh2, (int)sl2);
        pl32_t w3a = pl32((int)sl3, (int)sh3);
        pl32_t w3b = pl32((int)sh3, (int)sl3);
        uint32_t R0 = low ? (uint32_t)w0a.y : (uint32_t)w0b.x;
        uint32_t R1 = low ? (uint32_t)w1a.y : (uint32_t)w1b.x;
        uint32_t R2 = low ? (uint32_t)w2a.y : (uint32_t)w2b.x;
        uint32_t R3 = low ? (uint32_t)w3a.y : (uint32_t)w3b.x;
        uint32_t R4 = low ? (uint32_t)w0b.y : (uint32_t)w0a.x;
        uint32_t R5 = low ? (uint32_t)w1b.y : (uint32_t)w1a.x;
        uint32_t R6 = low ? (uint32_t)w2b.y : (uint32_t)w2a.x;
        uint32_t R7 = low ? (uint32_t)w3b.y : (uint32_t)w3a.x;
        uint32_t A0 = (g == 0) ? P2[0][0] : ((g == 3) ? q10 : R0);
        uint32_t A1 = (g == 0) ? P2[0][1] : ((g == 3) ? q11 : R1);
        uint32_t A2 = (g == 0) ? P2[2][0] : ((g == 3) ? q30 : R2);
        uint32_t A3 = (g == 0) ? P2[2][1] : ((g == 3) ? q31 : R3);
        uint32_t B0 = (g == 0) ? q00 : ((g == 3) ? P2[1][0] : R4);
        uint32_t B1 = (g == 0) ? q01 : ((g == 3) ? P2[1][1] : R5);
        uint32_t B2 = (g == 0) ? q20 : ((g == 3) ? P2[3][0] : R6);
        uint32_t B3 = (g == 0) ? q21 : ((g == 3) ? P2[3][1] : R7);
        union { uint32_t u[4]; f16x8 h; } U0, U1;
        U0.u[0] = A0; U0.u[1] = A1; U0.u[2] = B0; U0.u[3] = B1;   // k = 8g .. 8g+7
        U1.u[0] = A2; U1.u[1] = A3; U1.u[2] = B2; U1.u[3] = B3;   // k = 32+8g ..
        pa0 = U0.h; pa1 = U1.h;
    };

    auto pv = [&](int vb) {
        // two passes: dependent O[i] MFMAs sit 16 apart, not back-to-back
        __builtin_amdgcn_s_setprio(1);
        #pragma unroll
        for (int i = 0; i < 16; ++i) {
            f16x8 vb0 = *(const f16x8*)&sVt[vb][i * 16 + l15][khalf ^ rsw];
            O[i] = MFMA_F16(pa0, vb0, O[i]);
        }
        #pragma unroll
        for (int i = 0; i < 16; ++i) {
            f16x8 vb1 = *(const f16x8*)&sVt[vb][i * 16 + l15][(32 + khalf) ^ rsw];
            O[i] = MFMA_F16(pa1, vb1, O[i]);
        }
        __builtin_amdgcn_s_setprio(0);
    };

    if constexpr (PREP) {
        // prologue: tile 0 staged+computed; tile 1 staged
        stageK(0, 0); stageV(0, 0);
        __syncthreads();                    // implicit vmcnt(0): tile 0 landed
        stageK(1, BK); stageV(1, BK);
        qkt(0);
        softmax();                          // pa for tile 0
        // region ti: [bar] stage(ti+2) | QKT(ti+1) | PV(ti) | softmax(ti+1)
        for (int ti = 0; ti < NT; ++ti) {
            __syncthreads();                // stage(ti+1) landed; prior reads done
            if (ti + 2 < NT) {
                stageK(ti & 1, (ti + 2) * BK);        // last read by QKT(ti), prev region
                stageV((ti + 2) % 3, (ti + 2) * BK);  // last read by PV(ti-1), prev region
            }
            if (ti + 1 < NT) qkt((ti + 1) & 1);
            pv(ti % 3);
            if (ti + 1 < NT) softmax();     // pa for tile ti+1 (overlaps PV in flight)
        }
    } else {
        const int fr = t & 63, fc = (t >> 6) * 32;
        const int fsw = (fr & 7) << 3;
        for (int ti = 0; ti < NT; ++ti) {
            const int m0 = ti * BK;
            __syncthreads();
            #pragma unroll
            for (int e = 0; e < 32; e += 4) {
                float4 kv = *(const float4*)&ksrc[(size_t)(m0 + fr) * Cc + fc + e];
                sK[0][fr][(fc + e + 0) ^ fsw] = (_Float16)kv.x;
                sK[0][fr][(fc + e + 1) ^ fsw] = (_Float16)kv.y;
                sK[0][fr][(fc + e + 2) ^ fsw] = (_Float16)kv.z;
                sK[0][fr][(fc + e + 3) ^ fsw] = (_Float16)kv.w;
                float4 xv = *(const float4*)&qsrc[(size_t)(m0 + fr) * Cc + fc + e];
                sVt[0][fc + e + 0][fr ^ (((fc + e + 0) & 7) << 3)] = (_Float16)xv.x;
                sVt[0][fc + e + 1][fr ^ (((fc + e + 1) & 7) << 3)] = (_Float16)xv.y;
                sVt[0][fc + e + 2][fr ^ (((fc + e + 2) & 7) << 3)] = (_Float16)xv.z;
                sVt[0][fc + e + 3][fr ^ (((fc + e + 3) & 7) << 3)] = (_Float16)xv.w;
            }
            __syncthreads();
            qkt(0);
            softmax();
            pv(0);
        }
    }

    // ---- epilogue: row-sum (over g-copies), broadcast to O-rows, write ----
    float lv = lsum;
    lv += __shfl_xor(lv, 16, 64);
    {   // xor-32 sum via permlane32_swap
        pl32_t se = pl32(__float_as_int(lv), __float_as_int(lv));
        lv = __int_as_float(se.x) + __int_as_float(se.y);
    }
    const float gma = gamma_p[0];
    const int base = lane & 48;
    const int g4 = (g & 3) * 4;
    #pragma unroll
    for (int r = 0; r < 4; ++r) {
        const float lvr = __shfl(lv, base | (g4 + r), 64);
        const float inv = 1.f / lvr;
        const int row = qtile * BQ + w * 16 + g4 + r;
        const size_t ro = (size_t)row * Cc + l15;
        #pragma unroll
        for (int i = 0; i < 16; ++i) {
            float o = O[i][r] * inv;
            outp[ro + i * 16] = gma * o + qsrc[ro + i * 16];
        }
    }
}

extern "C" void kernel_launch(void* const* d_in, const int* in_sizes, int n_in,
                              void* d_out, int out_size, void* d_ws, size_t ws_size,
                              hipStream_t stream) {
    (void)in_sizes; (void)n_in; (void)out_size;
    const float* xa = (const float*)d_in[0];
    const float* xb = (const float*)d_in[1];
    const float* gm = (const float*)d_in[2];
    float* out = (float*)d_out;

    dim3 agrid(256);    // 1-D: bid&7 = (dir,b) -> XCD grouping under round-robin
    if (ws_size >= WS_NEED) {
        _Float16* hi = (_Float16*)d_ws;
        _Float16* lo = hi + ASZ;
        _Float16* vt = lo + ASZ;
        prep_kernel<<<dim3(Nn / 64, Cc / 64, 2 * Bb), 256, 0, stream>>>(xa, xb, hi, lo, vt);
        attn_kernel<true><<<agrid, 512, 0, stream>>>(xa, xb, gm, out, hi, lo, vt);
    } else {
        attn_kernel<false><<<agrid, 512, 0, stream>>>(xa, xb, gm, out, nullptr, nullptr, nullptr);
    }
}

// Round 17
// 208.631 us; speedup vs baseline: 1.0657x; 1.0657x over previous
//
#include <hip/hip_runtime.h>
#include <hip/hip_bf16.h>
#include <stdint.h>

typedef _Float16 f16x8 __attribute__((ext_vector_type(8)));
typedef __fp16 fp16x2_t __attribute__((ext_vector_type(2)));
typedef float f32x4 __attribute__((ext_vector_type(4)));

#define MFMA_F16(A, B, C) __builtin_amdgcn_mfma_f32_16x16x32_f16(A, B, C, 0, 0, 0)
#define GLOAD_LDS16(g, l)                                                     \
    __builtin_amdgcn_global_load_lds(                                         \
        (const __attribute__((address_space(1))) void*)(g),                   \
        (__attribute__((address_space(3))) void*)(l), 16, 0, 0)

constexpr int Bb = 4, Nn = 4096, Cc = 256;
constexpr int BQ = 128;          // q rows per block (8 waves x 16)
constexpr int BK = 64;           // k/v rows per tile
constexpr int NT = Nn / BK;
constexpr int KPAD = 256;        // 512B row stride; swizzle via pre-swizzled source
constexpr int VPAD = 64;         // 128B row stride; swizzle via pre-swizzled source
// LDS: 2*sK 65536 + 3*sVt 98304 = 163840 B (== 160KiB cap).
// K dbuf (write->read gap 1 region), V tribuf (gap 2 regions: PV(ti) runs one
// region after QKT(ti); tribuf avoids DMA-write vs PV-read race w/o extra barrier)

constexpr size_t ASZ = (size_t)2 * Bb * Nn * Cc;     // elems per ws array
constexpr size_t WS_NEED = ASZ * 2 * 3;              // bytes: hi + lo + vt

__device__ __forceinline__ uint32_t pk16(float a, float b) {
    union { fp16x2_t h; uint32_t u; } cv;
    cv.h = __builtin_amdgcn_cvt_pkrtz(a, b);
    return cv.u;
}

// ---------------- prep: fp32 -> fp16 hi/lo + transposed hi ----------------
__global__ __launch_bounds__(256)
void prep_kernel(const float* __restrict__ xa, const float* __restrict__ xb,
                 _Float16* __restrict__ hi, _Float16* __restrict__ lo,
                 _Float16* __restrict__ vt)
{
    const int n0 = blockIdx.x * 64, c0 = blockIdx.y * 64, ib = blockIdx.z;
    const float* x = ((ib >> 2) == 0 ? xa : xb) + (size_t)(ib & 3) * Nn * Cc;
    const size_t base = (size_t)ib * Nn * Cc;
    __shared__ ushort tile[64][68];
    const int t = threadIdx.x;
    const int r0 = t >> 4;            // 0..15
    const int c4 = (t & 15) * 4;      // 0,4,..,60
    #pragma unroll
    for (int ii = 0; ii < 4; ++ii) {
        const int r = r0 + ii * 16;
        float4 v = *(const float4*)&x[(size_t)(n0 + r) * Cc + c0 + c4];
        float vv[4] = {v.x, v.y, v.z, v.w};
        union { _Float16 h[4]; uint2 q; } H, L;
        #pragma unroll
        for (int e = 0; e < 4; ++e) {
            _Float16 h = (_Float16)vv[e];
            H.h[e] = h;
            L.h[e] = (_Float16)(vv[e] - (float)h);
        }
        *(uint2*)&hi[base + (size_t)(n0 + r) * Cc + c0 + c4] = H.q;
        *(uint2*)&lo[base + (size_t)(n0 + r) * Cc + c0 + c4] = L.q;
        *(uint2*)&tile[r][c4] = H.q;
    }
    __syncthreads();
    const int j4 = (t & 15) * 4;
    #pragma unroll
    for (int ii = 0; ii < 4; ++ii) {
        const int cr = r0 + ii * 16;
        ushort4 o;
        o.x = tile[j4 + 0][cr]; o.y = tile[j4 + 1][cr];
        o.z = tile[j4 + 2][cr]; o.w = tile[j4 + 3][cr];
        *(ushort4*)&vt[base + (size_t)(c0 + cr) * Nn + n0 + j4] = o;
    }
}

// ---------------- main attention ----------------
// grid = 256 1-D; bid&7 = (dir,b): round-robin block->XCD dispatch groups all 32
// q-tiles of one (dir,b) on ONE XCD (K 2MB + V^T 2MB fit its 4MB L2; FETCH 163->49MB).
template<bool PREP>
__global__ __launch_bounds__(512, 1)
void attn_kernel(const float* __restrict__ xa, const float* __restrict__ xb,
                 const float* __restrict__ gamma_p, float* __restrict__ out,
                 const _Float16* __restrict__ hi, const _Float16* __restrict__ lo,
                 const _Float16* __restrict__ vt)
{
    const int bid = blockIdx.x;
    const int qtile = bid >> 3, b = bid & 3, dir = (bid >> 2) & 1;
    const float* qsrc = (dir == 0 ? xa : xb) + (size_t)b * Nn * Cc;
    const float* ksrc = (dir == 0 ? xb : xa) + (size_t)b * Nn * Cc;
    float* outp = out + (size_t)dir * Bb * Nn * Cc + (size_t)b * Nn * Cc;
    const int qib = dir * Bb + b;
    const int kib = (dir ^ 1) * Bb + b;
    const _Float16* qhiB = hi + (size_t)qib * Nn * Cc;
    const _Float16* qloB = lo + (size_t)qib * Nn * Cc;
    const _Float16* kB   = hi + (size_t)kib * Nn * Cc;
    const _Float16* vtB  = vt + (size_t)qib * Nn * Cc;   // V^T of q-source

    __shared__ _Float16 sK[2][BK][KPAD];    // K (fp16 hi); swizzled via source
    __shared__ _Float16 sVt[3][Cc][VPAD];   // sVt[c][m] = V[m][c]; swizzled via source

    const int t = threadIdx.x, lane = t & 63, w = t >> 6;
    const int l15 = lane & 15, g = lane >> 4;
    const int khalf = g * 8;
    const int rsw = (l15 & 7) << 3;         // read swizzle (row = *16 + l15)

    // ---- Q fragments, negated (MFMA yields logits = -E), fp16 hi/lo ----
    f16x8 qhi[8], qlo[8];
    const int qrow = qtile * BQ + w * 16 + l15;
    if constexpr (PREP) {
        #pragma unroll
        for (int j = 0; j < 8; ++j) {
            union { uint4 u; f16x8 h; } A, C2;
            A.u  = *(const uint4*)(qhiB + (size_t)qrow * Cc + j * 32 + khalf);
            C2.u = *(const uint4*)(qloB + (size_t)qrow * Cc + j * 32 + khalf);
            A.u.x ^= 0x80008000u; A.u.y ^= 0x80008000u; A.u.z ^= 0x80008000u; A.u.w ^= 0x80008000u;
            C2.u.x ^= 0x80008000u; C2.u.y ^= 0x80008000u; C2.u.z ^= 0x80008000u; C2.u.w ^= 0x80008000u;
            qhi[j] = A.h; qlo[j] = C2.h;
        }
    } else {
        const float* qb = qsrc + (size_t)qrow * Cc;
        #pragma unroll
        for (int j = 0; j < 8; ++j) {
            float4 v0 = *(const float4*)(qb + j * 32 + khalf);
            float4 v1 = *(const float4*)(qb + j * 32 + khalf + 4);
            float xv[8] = {v0.x, v0.y, v0.z, v0.w, v1.x, v1.y, v1.z, v1.w};
            #pragma unroll
            for (int e = 0; e < 8; ++e) {
                float xn = -xv[e];
                _Float16 h = (_Float16)xn;
                qhi[j][e] = h;
                qlo[j][e] = (_Float16)(xn - (float)h);
            }
        }
    }

    f32x4 O[16];
    #pragma unroll
    for (int i = 0; i < 16; ++i) O[i] = (f32x4){0.f, 0.f, 0.f, 0.f};
    float mrow = -INFINITY;     // running max for q-row l15 (S^T domain, per-lane)
    float lsum = 0.f;           // partial sum for q-row l15 over this lane's k-slice

    f32x4 S[4];                 // current S^T tile (constant-indexed only)
    f16x8 pa0, pa1;             // loop-carried P fragments (computed one region early)

    // ---- global_load_lds staging maps: linear LDS dest, pre-swizzled source ----
    const int krow0 = w * 8;
    const int klsub = lane >> 5;            // row within inst (0..1)
    int offK[4];
    #pragma unroll
    for (int i = 0; i < 4; ++i) {
        const int rsub = i * 2 + klsub;                     // row mod 8 (krow0 % 8 == 0)
        const int sc = ((lane & 31) * 8) ^ ((rsub & 7) << 3);
        offK[i] = (krow0 + rsub) * Cc + sc;
    }
    const int vrow0 = w * 32;
    const int vlsub = lane >> 3;            // row within inst (0..7) == row mod 8
    const int vcol  = ((lane & 7) * 8) ^ ((vlsub & 7) << 3);
    int offV[4];
    #pragma unroll
    for (int i = 0; i < 4; ++i)
        offV[i] = (vrow0 + i * 8 + vlsub) * Nn + vcol;

    auto stageK = [&](int bufi, int m0) {
        #pragma unroll
        for (int i = 0; i < 4; ++i)
            GLOAD_LDS16(kB + (size_t)m0 * Cc + offK[i], &sK[bufi][krow0 + i * 2][0]);
    };
    auto stageV = [&](int vbi, int m0) {
        #pragma unroll
        for (int i = 0; i < 4; ++i)
            GLOAD_LDS16(vtB + (size_t)m0 + offV[i], &sVt[vbi][vrow0 + i * 8][0]);
    };

    auto qkt = [&](int kb) {
        // S^T = K (-Q)^T : swapped operands. Lane (l15,g): q-row=l15, k=16s+4g+r.
        #pragma unroll
        for (int s = 0; s < 4; ++s) S[s] = (f32x4){0.f, 0.f, 0.f, 0.f};
        __builtin_amdgcn_s_setprio(1);
        #pragma unroll
        for (int j = 0; j < 8; ++j) {
            const int ko = j * 32 + khalf;
            f16x8 k0 = *(const f16x8*)&sK[kb][l15][ko ^ rsw];
            f16x8 k1 = *(const f16x8*)&sK[kb][16 + l15][ko ^ rsw];
            f16x8 k2 = *(const f16x8*)&sK[kb][32 + l15][ko ^ rsw];
            f16x8 k3 = *(const f16x8*)&sK[kb][48 + l15][ko ^ rsw];
            S[0] = MFMA_F16(k0, qhi[j], S[0]);
            S[1] = MFMA_F16(k1, qhi[j], S[1]);
            S[2] = MFMA_F16(k2, qhi[j], S[2]);
            S[3] = MFMA_F16(k3, qhi[j], S[3]);
            S[0] = MFMA_F16(k0, qlo[j], S[0]);
            S[1] = MFMA_F16(k1, qlo[j], S[1]);
            S[2] = MFMA_F16(k2, qlo[j], S[2]);
            S[3] = MFMA_F16(k3, qlo[j], S[3]);
        }
        __builtin_amdgcn_s_setprio(0);
    };

    auto softmax = [&]() {
        // consumes S -> produces pa0/pa1; updates mrow/lsum; rescales O (rare)
        float tm = fmaxf(fmaxf(fmaxf(S[0][0], S[0][1]), fmaxf(S[0][2], S[0][3])),
                         fmaxf(fmaxf(S[1][0], S[1][1]), fmaxf(S[1][2], S[1][3])));
        tm = fmaxf(tm, fmaxf(fmaxf(fmaxf(S[2][0], S[2][1]), fmaxf(S[2][2], S[2][3])),
                             fmaxf(fmaxf(S[3][0], S[3][1]), fmaxf(S[3][2], S[3][3]))));
        tm = fmaxf(tm, __shfl_xor(tm, 16, 64));
        tm = fmaxf(tm, __shfl_xor(tm, 32, 64));
        const bool need = tm > mrow + 8.f;
        if (__any(need)) {      // rescale path (rare: defer-max THR=8)
            float mn = fmaxf(mrow, tm);
            float a = __expf(mrow - mn);
            mrow = mn;
            lsum *= a;
            const int base = lane & 48;
            const int g4 = (g & 3) * 4;
            float a0 = __shfl(a, base | (g4 + 0), 64);
            float a1 = __shfl(a, base | (g4 + 1), 64);
            float a2 = __shfl(a, base | (g4 + 2), 64);
            float a3 = __shfl(a, base | (g4 + 3), 64);
            #pragma unroll
            for (int i = 0; i < 16; ++i) {
                O[i][0] *= a0; O[i][1] *= a1; O[i][2] *= a2; O[i][3] *= a3;
            }
        }
        uint32_t P2[4][2];
        float ps = 0.f;
        #pragma unroll
        for (int s = 0; s < 4; ++s) {
            float p0 = __expf(S[s][0] - mrow);
            float p1 = __expf(S[s][1] - mrow);
            float p2 = __expf(S[s][2] - mrow);
            float p3 = __expf(S[s][3] - mrow);
            ps += (p0 + p1) + (p2 + p3);
            P2[s][0] = pk16(p0, p1);
            P2[s][1] = pk16(p2, p3);
        }
        lsum += ps;
        // butterfly: redistribute P into PV A-fragments (no LDS round-trip)
        uint32_t q00 = __shfl_xor(P2[0][0], 16, 64);
        uint32_t q01 = __shfl_xor(P2[0][1], 16, 64);
        uint32_t q10 = __shfl_xor(P2[1][0], 16, 64);
        uint32_t q11 = __shfl_xor(P2[1][1], 16, 64);
        uint32_t q20 = __shfl_xor(P2[2][0], 16, 64);
        uint32_t q21 = __shfl_xor(P2[2][1], 16, 64);
        uint32_t q30 = __shfl_xor(P2[3][0], 16, 64);
        uint32_t q31 = __shfl_xor(P2[3][1], 16, 64);
        const bool low = (g < 2);
        const bool odd = (g & 1);
        uint32_t m0_ = low ? P2[1][0] : P2[0][0];
        uint32_t m1_ = low ? P2[1][1] : P2[0][1];
        uint32_t m2_ = low ? P2[3][0] : P2[2][0];
        uint32_t m3_ = low ? P2[3][1] : P2[2][1];
        uint32_t p0_ = low ? q10 : q00;
        uint32_t p1_ = low ? q11 : q01;
        uint32_t p2_ = low ? q30 : q20;
        uint32_t p3_ = low ? q31 : q21;
        uint32_t sl0 = odd ? p0_ : m0_, sh0 = odd ? m0_ : p0_;
        uint32_t sl1 = odd ? p1_ : m1_, sh1 = odd ? m1_ : p1_;
        uint32_t sl2 = odd ? p2_ : m2_, sh2 = odd ? m2_ : p2_;
        uint32_t sl3 = odd ? p3_ : m3_, sh3 = odd ? m3_ : p3_;
        uint32_t R0 = __shfl_xor(sl0, 32, 64);
        uint32_t R1 = __shfl_xor(sl1, 32, 64);
        uint32_t R2 = __shfl_xor(sl2, 32, 64);
        uint32_t R3 = __shfl_xor(sl3, 32, 64);
        uint32_t R4 = __shfl_xor(sh0, 32, 64);
        uint32_t R5 = __shfl_xor(sh1, 32, 64);
        uint32_t R6 = __shfl_xor(sh2, 32, 64);
        uint32_t R7 = __shfl_xor(sh3, 32, 64);
        uint32_t A0 = (g == 0) ? P2[0][0] : ((g == 3) ? q10 : R0);
        uint32_t A1 = (g == 0) ? P2[0][1] : ((g == 3) ? q11 : R1);
        uint32_t A2 = (g == 0) ? P2[2][0] : ((g == 3) ? q30 : R2);
        uint32_t A3 = (g == 0) ? P2[2][1] : ((g == 3) ? q31 : R3);
        uint32_t B0 = (g == 0) ? q00 : ((g == 3) ? P2[1][0] : R4);
        uint32_t B1 = (g == 0) ? q01 : ((g == 3) ? P2[1][1] : R5);
        uint32_t B2 = (g == 0) ? q20 : ((g == 3) ? P2[3][0] : R6);
        uint32_t B3 = (g == 0) ? q21 : ((g == 3) ? P2[3][1] : R7);
        union { uint32_t u[4]; f16x8 h; } U0, U1;
        U0.u[0] = A0; U0.u[1] = A1; U0.u[2] = B0; U0.u[3] = B1;   // k = 8g .. 8g+7
        U1.u[0] = A2; U1.u[1] = A3; U1.u[2] = B2; U1.u[3] = B3;   // k = 32+8g ..
        pa0 = U0.h; pa1 = U1.h;
    };

    auto pv = [&](int vb) {
        // two passes: dependent O[i] MFMAs sit 16 apart, not back-to-back
        __builtin_amdgcn_s_setprio(1);
        #pragma unroll
        for (int i = 0; i < 16; ++i) {
            f16x8 vb0 = *(const f16x8*)&sVt[vb][i * 16 + l15][khalf ^ rsw];
            O[i] = MFMA_F16(pa0, vb0, O[i]);
        }
        #pragma unroll
        for (int i = 0; i < 16; ++i) {
            f16x8 vb1 = *(const f16x8*)&sVt[vb][i * 16 + l15][(32 + khalf) ^ rsw];
            O[i] = MFMA_F16(pa1, vb1, O[i]);
        }
        __builtin_amdgcn_s_setprio(0);
    };

    if constexpr (PREP) {
        // prologue: tile 0 staged+computed; tile 1 staged
        stageK(0, 0); stageV(0, 0);
        __syncthreads();                    // implicit vmcnt(0): tile 0 landed
        stageK(1, BK); stageV(1, BK);
        qkt(0);
        softmax();                          // pa for tile 0
        // region ti: [bar] QKT(ti+1) | stage(ti+2) | PV(ti) | softmax(ti+1)
        for (int ti = 0; ti < NT; ++ti) {
            __syncthreads();                // stage(ti+1) landed; prior reads done
            if (ti + 1 < NT) qkt((ti + 1) & 1);
            if (ti + 2 < NT) {
                stageK(ti & 1, (ti + 2) * BK);        // last read by QKT(ti), prev region
                stageV((ti + 2) % 3, (ti + 2) * BK);  // last read by PV(ti-1), prev region
            }
            pv(ti % 3);
            if (ti + 1 < NT) softmax();     // pa for tile ti+1 (overlaps PV in flight)
        }
    } else {
        const int fr = t & 63, fc = (t >> 6) * 32;
        const int fsw = (fr & 7) << 3;
        for (int ti = 0; ti < NT; ++ti) {
            const int m0 = ti * BK;
            __syncthreads();
            #pragma unroll
            for (int e = 0; e < 32; e += 4) {
                float4 kv = *(const float4*)&ksrc[(size_t)(m0 + fr) * Cc + fc + e];
                sK[0][fr][(fc + e + 0) ^ fsw] = (_Float16)kv.x;
                sK[0][fr][(fc + e + 1) ^ fsw] = (_Float16)kv.y;
                sK[0][fr][(fc + e + 2) ^ fsw] = (_Float16)kv.z;
                sK[0][fr][(fc + e + 3) ^ fsw] = (_Float16)kv.w;
                float4 xv = *(const float4*)&qsrc[(size_t)(m0 + fr) * Cc + fc + e];
                sVt[0][fc + e + 0][fr ^ (((fc + e + 0) & 7) << 3)] = (_Float16)xv.x;
                sVt[0][fc + e + 1][fr ^ (((fc + e + 1) & 7) << 3)] = (_Float16)xv.y;
                sVt[0][fc + e + 2][fr ^ (((fc + e + 2) & 7) << 3)] = (_Float16)xv.z;
                sVt[0][fc + e + 3][fr ^ (((fc + e + 3) & 7) << 3)] = (_Float16)xv.w;
            }
            __syncthreads();
            qkt(0);
            softmax();
            pv(0);
        }
    }

    // ---- epilogue: row-sum (over g-copies), broadcast to O-rows, write ----
    float lv = lsum;
    lv += __shfl_xor(lv, 16, 64);
    lv += __shfl_xor(lv, 32, 64);           // full row-sum for q-row l15, all copies
    const float gma = gamma_p[0];
    const int base = lane & 48;
    const int g4 = (g & 3) * 4;
    #pragma unroll
    for (int r = 0; r < 4; ++r) {
        const float lvr = __shfl(lv, base | (g4 + r), 64);
        const float inv = 1.f / lvr;
        const int row = qtile * BQ + w * 16 + g4 + r;
        const size_t ro = (size_t)row * Cc + l15;
        #pragma unroll
        for (int i = 0; i < 16; ++i) {
            float o = O[i][r] * inv;
            outp[ro + i * 16] = gma * o + qsrc[ro + i * 16];
        }
    }
}

extern "C" void kernel_launch(void* const* d_in, const int* in_sizes, int n_in,
                              void* d_out, int out_size, void* d_ws, size_t ws_size,
                              hipStream_t stream) {
    (void)in_sizes; (void)n_in; (void)out_size;
    const float* xa = (const float*)d_in[0];
    const float* xb = (const float*)d_in[1];
    const float* gm = (const float*)d_in[2];
    float* out = (float*)d_out;

    dim3 agrid(256);    // 1-D: bid&7 = (dir,b) -> XCD grouping under round-robin
    if (ws_size >= WS_NEED) {
        _Float16* hi = (_Float16*)d_ws;
        _Float16* lo = hi + ASZ;
        _Float16* vt = lo + ASZ;
        prep_kernel<<<dim3(Nn / 64, Cc / 64, 2 * Bb), 256, 0, stream>>>(xa, xb, hi, lo, vt);
        attn_kernel<true><<<agrid, 512, 0, stream>>>(xa, xb, gm, out, hi, lo, vt);
    } else {
        attn_kernel<false><<<agrid, 512, 0, stream>>>(xa, xb, gm, out, nullptr, nullptr, nullptr);
    }
}